// Round 1
// baseline (435.200 us; speedup 1.0000x reference)
//
#include <hip/hip_runtime.h>

typedef __attribute__((ext_vector_type(8))) short  short8;   // 8 x bf16 bits = 4 VGPR
typedef __attribute__((ext_vector_type(4))) float  float4v;  // MFMA C/D + global float4
typedef __attribute__((ext_vector_type(2))) int    int2v;    // 8-byte LDS store

#define E_TILE 64
#define LDA    264   // 256 + 8 bf16 pad (breaks 512B stride)
#define LDH    136   // 128 + 8 pad
#define PGRID  512   // persistent grid: 2 blocks/CU x 256 CU

// fp32 -> bf16 bits, round-to-nearest-even (used for weight prologue)
__device__ __forceinline__ short f2bf(float f) {
    union { float f; unsigned u; } v; v.f = f;
    unsigned r = (v.u + 0x7FFFu + ((v.u >> 16) & 1u)) >> 16;
    return (short)r;
}

__global__ __launch_bounds__(256, 2)
void edge_mlp_kernel(const float* __restrict__ x,
                     const int*   __restrict__ ei,
                     const float* __restrict__ W1,
                     const float* __restrict__ b1,
                     const float* __restrict__ W2,
                     const float* __restrict__ b2,
                     float*       __restrict__ out,
                     int E, int nTiles) {
    __shared__ short sA[E_TILE * LDA];   // gathered [src||dst] tile, bf16
    __shared__ short sH[E_TILE * LDH];   // hidden tile, bf16
    __shared__ int   sIdx[2][2 * E_TILE];

    const int tid  = threadIdx.x;
    const int wave = tid >> 6;
    const int lane = tid & 63;
    const int quad = lane >> 4;
    const int l16  = lane & 15;
    const int nBase = wave * 32;         // each wave owns N-slice [nBase, nBase+32)
    const int G = gridDim.x;

    // ---- persistent weight preload: B-fragments in registers, ONCE per block ----
    // B layout for mfma_16x16x32: lane holds B[k = quad*8+j][n = lane&15]
    short8 bw1[8][2];   // K1=256 -> 8 k-steps of 32; 2 n-tiles of 16
    short8 bw2[4][2];   // K2=128 -> 4 k-steps
    #pragma unroll
    for (int kt = 0; kt < 8; ++kt)
        #pragma unroll
        for (int nt = 0; nt < 2; ++nt) {
            short8 f;
            #pragma unroll
            for (int j = 0; j < 8; ++j) {
                int k = kt * 32 + quad * 8 + j;
                int n = nBase + nt * 16 + l16;
                f[j] = f2bf(W1[k * 128 + n]);
            }
            bw1[kt][nt] = f;
        }
    #pragma unroll
    for (int kt = 0; kt < 4; ++kt)
        #pragma unroll
        for (int nt = 0; nt < 2; ++nt) {
            short8 f;
            #pragma unroll
            for (int j = 0; j < 8; ++j) {
                int k = kt * 32 + quad * 8 + j;
                int n = nBase + nt * 16 + l16;
                f[j] = f2bf(W2[k * 128 + n]);
            }
            bw2[kt][nt] = f;
        }
    float b1v[2], b2v[2];
    #pragma unroll
    for (int nt = 0; nt < 2; ++nt) {
        b1v[nt] = b1[nBase + nt * 16 + l16];
        b2v[nt] = b2[nBase + nt * 16 + l16];
    }

    // ---- helpers ----
    auto stageIdx = [&](int b, int t) {
        if (tid < E_TILE) {
            int s = 0, d = 0;
            if (t < nTiles) {
                long eg = (long)t * E_TILE + tid;
                if (eg < (long)E) { s = ei[eg]; d = ei[(long)E + eg]; }
            }
            sIdx[b][tid] = s;
            sIdx[b][E_TILE + tid] = d;
        }
    };

    // gather 64 edges x 256 fp32 -> bf16 into sA (reads sIdx[b])
    auto gather = [&](int b) {
        #pragma unroll
        for (int i = 0; i < 16; ++i) {
            int f = tid + 256 * i;     // float4 index in [0,4096)
            int e = f >> 6;            // per-wave uniform edge row
            int c = f & 63;            // lane = float4 within the 256-float row
            int node = (c < 32) ? sIdx[b][e] : sIdx[b][E_TILE + e];
            int cc = c & 31;
            float4v v = *(const float4v*)&x[(long)node * 128 + cc * 4];
            unsigned lo, hi;
            asm("v_cvt_pk_bf16_f32 %0, %1, %2" : "=v"(lo) : "v"(v.x), "v"(v.y));
            asm("v_cvt_pk_bf16_f32 %0, %1, %2" : "=v"(hi) : "v"(v.z), "v"(v.w));
            int2v s; s.x = (int)lo; s.y = (int)hi;
            *(int2v*)&sA[e * LDA + c * 4] = s;
        }
    };

    // ---- prologue: stage idx(t0), gather tile t0, stage idx(t0+G) ----
    const int t0 = blockIdx.x;
    if (t0 >= nTiles) return;
    stageIdx(0, t0);
    __syncthreads();                 // sIdx[0] visible
    gather(0);
    stageIdx(1, t0 + G);
    __syncthreads();                 // sA(t0) + sIdx[1] visible

    int buf = 1;                     // buffer holding idx for the NEXT gather
    for (int t = t0; t < nTiles; t += G) {
        const long eBase = (long)t * E_TILE;

        // ---- GEMM1: H = relu(A @ W1 + b1), per-wave M=64 x N=32 ----
        float4v acc[4][2];
        #pragma unroll
        for (int mt = 0; mt < 4; ++mt)
            #pragma unroll
            for (int nt = 0; nt < 2; ++nt)
                acc[mt][nt] = (float4v)(0.0f);

        #pragma unroll
        for (int kt = 0; kt < 8; ++kt) {
            short8 a[4];
            #pragma unroll
            for (int mt = 0; mt < 4; ++mt)
                a[mt] = *(const short8*)&sA[(mt * 16 + l16) * LDA + kt * 32 + quad * 8];
            #pragma unroll
            for (int mt = 0; mt < 4; ++mt)
                #pragma unroll
                for (int nt = 0; nt < 2; ++nt)
                    acc[mt][nt] = __builtin_amdgcn_mfma_f32_16x16x32_bf16(
                        a[mt], bw1[kt][nt], acc[mt][nt], 0, 0, 0);
        }

        // C/D layout: col = lane&15, row = quad*4 + r
        #pragma unroll
        for (int mt = 0; mt < 4; ++mt)
            #pragma unroll
            for (int nt = 0; nt < 2; ++nt)
                #pragma unroll
                for (int r = 0; r < 4; ++r) {
                    int m = mt * 16 + quad * 4 + r;
                    int n = nBase + nt * 16 + l16;
                    float h = acc[mt][nt][r] + b1v[nt];
                    h = fmaxf(h, 0.0f);
                    sH[m * LDH + n] = f2bf(h);
                }

        __syncthreads();             // sH ready; sA free (all GEMM1 reads done)

        // ---- pipelined region: gather(t+G) overlaps GEMM2(t)+stores ----
        const bool hasNext = (t + G < nTiles);
        if (hasNext) gather(buf);    // loads issued first -> latency hides under MFMAs
        stageIdx(buf ^ 1, t + 2 * G);

        // ---- GEMM2: OUT = H @ W2 + b2 ----
        float4v acc2[4][2];
        #pragma unroll
        for (int mt = 0; mt < 4; ++mt)
            #pragma unroll
            for (int nt = 0; nt < 2; ++nt)
                acc2[mt][nt] = (float4v)(0.0f);

        #pragma unroll
        for (int kt = 0; kt < 4; ++kt) {
            short8 a[4];
            #pragma unroll
            for (int mt = 0; mt < 4; ++mt)
                a[mt] = *(const short8*)&sH[(mt * 16 + l16) * LDH + kt * 32 + quad * 8];
            #pragma unroll
            for (int mt = 0; mt < 4; ++mt)
                #pragma unroll
                for (int nt = 0; nt < 2; ++nt)
                    acc2[mt][nt] = __builtin_amdgcn_mfma_f32_16x16x32_bf16(
                        a[mt], bw2[kt][nt], acc2[mt][nt], 0, 0, 0);
        }

        // ---- epilogue: fp32 non-temporal stores (don't pollute L2; x lives there) ----
        #pragma unroll
        for (int mt = 0; mt < 4; ++mt)
            #pragma unroll
            for (int nt = 0; nt < 2; ++nt)
                #pragma unroll
                for (int r = 0; r < 4; ++r) {
                    int m = mt * 16 + quad * 4 + r;
                    long e = eBase + m;
                    if (e < (long)E) {
                        int n = nBase + nt * 16 + l16;
                        __builtin_nontemporal_store(acc2[mt][nt][r] + b2v[nt],
                                                    &out[e * 128 + n]);
                    }
                }

        __syncthreads();             // sA(t+G) ready; sH free
        buf ^= 1;
    }
}

extern "C" void kernel_launch(void* const* d_in, const int* in_sizes, int n_in,
                              void* d_out, int out_size, void* d_ws, size_t ws_size,
                              hipStream_t stream) {
    const float* x  = (const float*)d_in[0];
    const int*   ei = (const int*)d_in[1];
    const float* W1 = (const float*)d_in[2];
    const float* b1 = (const float*)d_in[3];
    const float* W2 = (const float*)d_in[4];
    const float* b2 = (const float*)d_in[5];
    float* out = (float*)d_out;
    int E = in_sizes[1] / 2;                     // edge_index is [2, E]
    int nTiles = (E + E_TILE - 1) / E_TILE;      // 600000/64 = 9375
    int grid = nTiles < PGRID ? nTiles : PGRID;  // persistent: ~18 tiles/block
    edge_mlp_kernel<<<grid, 256, 0, stream>>>(x, ei, W1, b1, W2, b2, out, E, nTiles);
}